// Round 13
// baseline (218.076 us; speedup 1.0000x reference)
//
#include <hip/hip_runtime.h>
#include <cstdint>

#define NBATCH 4
#define NPATCH 4096
#define MAXC   5
#define BM 64
#define BN 64
#define NSPLIT 8
#define SPLITCOLS (NPATCH / NSPLIT)         /* 512 cols per block */
#define NCIT (SPLITCOLS / BN)               /* 8 col-tiles per block */
#define NRBK (NBATCH * (NPATCH / BM))       /* 256 row-blocks */
#define SCALE  14.285714285714286f          /* 1/T, T=0.07 */
#define SCALE2 20.609929006188747f          /* (1/T) * log2(e) */
#define LN2F   0.6931471805599453f
#define NEGH  -1.0e38f
#define NEGFILL_T -142.85714285714286f      /* NEG_FILL / T */
#define NROWS (NBATCH * NPATCH)

typedef __attribute__((ext_vector_type(8))) short short8;   // 8 bf16 (4 VGPRs)
typedef __attribute__((ext_vector_type(4))) float f32x4;

__device__ __forceinline__ float fexp2(float x) { return __builtin_amdgcn_exp2f(x); }
__device__ __forceinline__ float flog2(float x) { return __builtin_amdgcn_logf(x); }  // v_log_f32 = log2

__device__ __forceinline__ unsigned short f2bf(float f) {
  uint32_t u = __builtin_bit_cast(uint32_t, f);
  u = (u + 0x7FFFu + ((u >> 16) & 1u)) >> 16;   // RNE
  return (unsigned short)u;
}

// Fragment layout (srcb and tgtb): tile = 16 rows x 256 k (8 KB).
// 16B chunk (8 bf16, one row's k-octet) at uint4 index  tile*512 + kc*16 + row16
// (kc = k/8, row16 = row%16).  A wave's fragment load (kc = ks*4+q, row = l4,
// lane = q*16+l4) is  base + ks*64 + lane : one fully-coalesced 1KB transaction.

// ---- k_aux: 3 roles ----
//  [0, 512):  single-pass: read src+tgt rows once -> srcb (pre-scaled bf16 frag),
//             tgtb (bf16 frag), AND exact-f32 pos via 8-lane shuffle reduce.
//  [512, 512+NBATCH): per-batch class scan (counts + stable ranks).
//  [512+NBATCH]: zero the per-row-block arrival counters (ws is poisoned each launch).
__global__ __launch_bounds__(256) void k_aux(const float* __restrict__ src,
                                             const float* __restrict__ tgt,
                                             const int* __restrict__ classes,
                                             unsigned short* __restrict__ tgtb,
                                             unsigned short* __restrict__ srcb,
                                             float* __restrict__ pos,
                                             int* __restrict__ outpos,
                                             int* __restrict__ counts,
                                             unsigned int* __restrict__ cnt) {
  int blk = blockIdx.x;
  if (blk < 512) {
    // block handles 2 tiles (32 rows); thread: one row's 32-k slab (8 threads/row)
    int t  = threadIdx.x;
    int tl = blk * 2 + (t >> 7);                 // tile index 0..1023
    int tt = t & 127;
    int row16 = tt >> 3;                         // 0..15
    int kg    = tt & 7;                          // 32 k each
    size_t rowbase = (size_t)(tl * 16 + row16) * 256 + kg * 32;
    const float4* rs = (const float4*)(src + rowbase);
    const float4* rt_ = (const float4*)(tgt + rowbase);
    uint4* wsrc = (uint4*)srcb + (size_t)tl * 512 + (size_t)(kg * 4) * 16 + row16;
    uint4* wtgt = (uint4*)tgtb + (size_t)tl * 512 + (size_t)(kg * 4) * 16 + row16;
    float d = 0.f;
#pragma unroll
    for (int j = 0; j < 4; ++j) {                // chunk kc = kg*4 + j
      float4 sa = rs[j * 2], sb = rs[j * 2 + 1];
      float4 ta = rt_[j * 2], tb = rt_[j * 2 + 1];
      d += sa.x * ta.x + sa.y * ta.y + sa.z * ta.z + sa.w * ta.w
         + sb.x * tb.x + sb.y * tb.y + sb.z * tb.z + sb.w * tb.w;
      union { ushort4 h[2]; uint4 u; } pk;
      pk.h[0].x = f2bf(sa.x * SCALE2); pk.h[0].y = f2bf(sa.y * SCALE2);
      pk.h[0].z = f2bf(sa.z * SCALE2); pk.h[0].w = f2bf(sa.w * SCALE2);
      pk.h[1].x = f2bf(sb.x * SCALE2); pk.h[1].y = f2bf(sb.y * SCALE2);
      pk.h[1].z = f2bf(sb.z * SCALE2); pk.h[1].w = f2bf(sb.w * SCALE2);
      wsrc[j * 16] = pk.u;
      pk.h[0].x = f2bf(ta.x); pk.h[0].y = f2bf(ta.y);
      pk.h[0].z = f2bf(ta.z); pk.h[0].w = f2bf(ta.w);
      pk.h[1].x = f2bf(tb.x); pk.h[1].y = f2bf(tb.y);
      pk.h[1].z = f2bf(tb.z); pk.h[1].w = f2bf(tb.w);
      wtgt[j * 16] = pk.u;
    }
    d += __shfl_xor(d, 1, 64);
    d += __shfl_xor(d, 2, 64);
    d += __shfl_xor(d, 4, 64);
    if (kg == 0) pos[tl * 16 + row16] = d * SCALE;
    return;
  }
  if (blk >= 512 + NBATCH) {
    // zero arrival counters
    if (threadIdx.x < NRBK) cnt[threadIdx.x] = 0u;
    return;
  }

  // ---- per-batch scan: counts + stable class-sorted output positions
  __shared__ int sa[MAXC * 256];
  __shared__ int sb2[MAXC * 256];
  int b = blk - 512, t = threadIdx.x;
  int base = b * NPATCH + t * 16;
  int cv[16];
#pragma unroll
  for (int e = 0; e < 16; ++e) cv[e] = classes[base + e];
  int cnt_[MAXC];
#pragma unroll
  for (int c = 0; c < MAXC; ++c) {
    cnt_[c] = 0;
#pragma unroll
    for (int e = 0; e < 16; ++e)
      if (cv[e] == c) cnt_[c]++;
  }
#pragma unroll
  for (int c = 0; c < MAXC; ++c) sa[c * 256 + t] = cnt_[c];
  __syncthreads();

  int* rp = sa; int* wp = sb2;
  for (int d = 1; d < 256; d <<= 1) {            // Hillis-Steele inclusive scan
#pragma unroll
    for (int c = 0; c < MAXC; ++c) {
      int v = rp[c * 256 + t];
      if (t >= d) v += rp[c * 256 + t - d];
      wp[c * 256 + t] = v;
    }
    __syncthreads();
    int* tmp = rp; rp = wp; wp = tmp;
  }

  int tot[MAXC], excl[MAXC], off[MAXC + 1];
  off[0] = 0;
#pragma unroll
  for (int c = 0; c < MAXC; ++c) {
    tot[c]  = rp[c * 256 + 255];
    excl[c] = rp[c * 256 + t] - cnt_[c];
    off[c + 1] = off[c] + tot[c];
  }
#pragma unroll
  for (int c = 0; c < MAXC; ++c) {
    int r = off[c] + excl[c];
#pragma unroll
    for (int e = 0; e < 16; ++e)
      if (cv[e] == c) { outpos[base + e] = r; r++; }
  }
  if (t < MAXC) counts[b * MAXC + t] = tot[t];
}

// ---------------- main fused GEMM + online lse stats (barrier-free K-loop) -------------
// R11 structure exactly (free-running waves; proven 57.5 us), plus fused finalization:
// the 8 split-blocks of each row-block write (m,s) partials; last arrival (device-scope
// atomic counter + threadfence release/acquire) merges them, applies the pad term, and
// scatters the class-sorted output. Eliminates the separate k_fin launch.
__global__ __launch_bounds__(256) void k_main(const unsigned short* __restrict__ srcb,
                                              const unsigned short* __restrict__ tgtb,
                                              const int* __restrict__ classes,
                                              float* __restrict__ pm,
                                              float* __restrict__ ps,
                                              const float* __restrict__ pos,
                                              const int* __restrict__ outpos,
                                              const int* __restrict__ counts,
                                              unsigned int* __restrict__ cnt,
                                              float* __restrict__ out) {
  __shared__ float redm[2][BM], reds[2][BM];

  const int blk   = blockIdx.x;
  const int split = blk & (NSPLIT - 1);          // == XCD id under HW round-robin
  const int rbk   = blk >> 3;
  const int b     = rbk >> 6;
  const int rb    = rbk & 63;
  const int rowstart = b * NPATCH + rb * BM;
  const int tid = threadIdx.x;
  const int w = tid >> 6, lane = tid & 63, q = lane >> 4, l4 = lane & 15;
  const int rh = w >> 1, ch = w & 1;
  const int colbase = b * NPATCH + split * SPLITCOLS;

  // ---- A fragments: 16 coalesced uint4 loads (pre-scaled bf16, fragment layout)
  const uint4* ap = (const uint4*)srcb + (size_t)(b * 256 + rb * 4 + rh * 2) * 512 + lane;
  uint4 afr[2][8];
#pragma unroll
  for (int rt = 0; rt < 2; ++rt)
#pragma unroll
    for (int ks = 0; ks < 8; ++ks)
      afr[rt][ks] = ap[rt * 512 + ks * 64];

  int rcls[2][4];
#pragma unroll
  for (int rt = 0; rt < 2; ++rt)
#pragma unroll
    for (int r = 0; r < 4; ++r)
      rcls[rt][r] = classes[rowstart + rh * 32 + rt * 16 + q * 4 + r];

  float m_[2][4], s_[2][4];
#pragma unroll
  for (int rt = 0; rt < 2; ++rt)
#pragma unroll
    for (int r = 0; r < 4; ++r) { m_[rt][r] = -INFINITY; s_[rt][r] = 0.f; }

  // ---- B-fragment pointer: wave's ch half starts at tile (b*256+split*32+ch*2)
  const uint4* bp = (const uint4*)tgtb
                  + (size_t)(b * 256 + split * 32 + ch * 2) * 512 + lane;
  const int* clp = classes + colbase + ch * 32 + l4;

  uint4 ea0[4], ea1[4], eb0[4], eb1[4];
#define LOADH(d0, d1, uoff)                                                         \
  {                                                                                 \
    _Pragma("unroll")                                                               \
    for (int i = 0; i < 4; ++i) {                                                   \
      d0[i] = bp[(uoff) + i * 64];                                                  \
      d1[i] = bp[(uoff) + i * 64 + 512];                                            \
    }                                                                               \
  }

#define STATS(ac, cc0, cc1)                                                         \
  {                                                                                 \
    _Pragma("unroll")                                                               \
    for (int rt = 0; rt < 2; ++rt) {                                                \
      _Pragma("unroll")                                                             \
      for (int r = 0; r < 4; ++r) {                                                 \
        int rc = rcls[rt][r];                                                       \
        float y0 = ((cc0) == rc) ? NEGH : (ac)[rt][0][r];                           \
        float y1 = ((cc1) == rc) ? NEGH : (ac)[rt][1][r];                           \
        float nm = fmaxf(m_[rt][r], fmaxf(y0, y1));                                 \
        float e01 = fexp2(y0 - nm) + fexp2(y1 - nm);                                \
        s_[rt][r] = fmaf(s_[rt][r], fexp2(m_[rt][r] - nm), e01);                    \
        m_[rt][r] = nm;                                                             \
      }                                                                             \
    }                                                                               \
  }

  LOADH(ea0, ea1, 0);                            // prologue: (cit0, kh0)

  const f32x4 zc = {0.f, 0.f, 0.f, 0.f};         // zero C operand (first MFMA of tile)
  f32x4 pacc[2][2];
  int pc0 = 0, pc1 = 0;

  for (int cit = 0; cit < NCIT; ++cit) {
    f32x4 acc[2][2];

    LOADH(eb0, eb1, cit * 2048 + 256);           // prefetch kh=1 of this tile
    int c0 = clp[cit * 64];
    int c1 = clp[cit * 64 + 16];

    // compute kh=0 from ea (eb loads in flight); first ksl uses zero-C
#pragma unroll
    for (int ksl = 0; ksl < 4; ++ksl) {
      short8 b0 = __builtin_bit_cast(short8, ea0[ksl]);
      short8 b1 = __builtin_bit_cast(short8, ea1[ksl]);
#pragma unroll
      for (int rt = 0; rt < 2; ++rt) {
        short8 a = __builtin_bit_cast(short8, afr[rt][ksl]);
        acc[rt][0] = __builtin_amdgcn_mfma_f32_16x16x32_bf16(
            a, b0, (ksl == 0) ? zc : acc[rt][0], 0, 0, 0);
        acc[rt][1] = __builtin_amdgcn_mfma_f32_16x16x32_bf16(
            a, b1, (ksl == 0) ? zc : acc[rt][1], 0, 0, 0);
      }
    }

    if (cit + 1 < NCIT) LOADH(ea0, ea1, (cit + 1) * 2048);   // prefetch next tile kh=0

    // stats on PREVIOUS tile's acc — covers both in-flight prefetches with VALU
    if (cit > 0) STATS(pacc, pc0, pc1);

    // compute kh=1 from eb
#pragma unroll
    for (int ksl = 0; ksl < 4; ++ksl) {
      short8 b0 = __builtin_bit_cast(short8, eb0[ksl]);
      short8 b1 = __builtin_bit_cast(short8, eb1[ksl]);
#pragma unroll
      for (int rt = 0; rt < 2; ++rt) {
        short8 a = __builtin_bit_cast(short8, afr[rt][4 + ksl]);
        acc[rt][0] = __builtin_amdgcn_mfma_f32_16x16x32_bf16(a, b0, acc[rt][0], 0, 0, 0);
        acc[rt][1] = __builtin_amdgcn_mfma_f32_16x16x32_bf16(a, b1, acc[rt][1], 0, 0, 0);
      }
    }

#pragma unroll
    for (int rt = 0; rt < 2; ++rt)
#pragma unroll
      for (int ct = 0; ct < 2; ++ct) pacc[rt][ct] = acc[rt][ct];
    pc0 = c0; pc1 = c1;
  }
  STATS(pacc, pc0, pc1);                         // epilogue: last tile's stats
#undef LOADH
#undef STATS

  // butterfly merge across the 16 col-lanes of each quad
#pragma unroll
  for (int off = 1; off < 16; off <<= 1) {
#pragma unroll
    for (int rt = 0; rt < 2; ++rt)
#pragma unroll
      for (int r = 0; r < 4; ++r) {
        float om = __shfl_xor(m_[rt][r], off, 64);
        float os = __shfl_xor(s_[rt][r], off, 64);
        float nm = fmaxf(m_[rt][r], om);
        s_[rt][r] = s_[rt][r] * fexp2(m_[rt][r] - nm) + os * fexp2(om - nm);
        m_[rt][r] = nm;
      }
  }

  if (l4 == 0) {
#pragma unroll
    for (int rt = 0; rt < 2; ++rt)
#pragma unroll
      for (int r = 0; r < 4; ++r) {
        int li = rh * 32 + rt * 16 + q * 4 + r;
        redm[ch][li] = m_[rt][r];
        reds[ch][li] = s_[rt][r];
      }
  }
  __syncthreads();

  // wave 0: write this split's partials, then last-arrival finalization
  if (w == 0) {
    float m0 = redm[0][lane], m1 = redm[1][lane];
    float nm = fmaxf(m0, m1);
    float s  = reds[0][lane] * fexp2(m0 - nm) + reds[1][lane] * fexp2(m1 - nm);
    size_t o = (size_t)split * NROWS + rowstart + lane;
    pm[o] = nm;                                   // log2 domain
    ps[o] = s;

    __threadfence();                              // release: partials visible device-wide
    int old = 0;
    if (lane == 0) old = (int)atomicAdd(&cnt[rbk], 1u);
    old = __shfl(old, 0, 64);
    if (old == NSPLIT - 1) {                      // last arrival merges + scatters
      __threadfence();                            // acquire
      int n = rowstart + lane;
      int c = classes[n];
      float ps_ = pos[n];
      float M2 = -INFINITY;
      float mm[NSPLIT], ss[NSPLIT];
#pragma unroll
      for (int s2 = 0; s2 < NSPLIT; ++s2) {
        mm[s2] = pm[(size_t)s2 * NROWS + n];
        ss[s2] = ps[(size_t)s2 * NROWS + n];
        M2 = fmaxf(M2, mm[s2]);
      }
      float S2 = 0.f;
#pragma unroll
      for (int s2 = 0; s2 < NSPLIT; ++s2) S2 = fmaf(ss[s2], fexp2(mm[s2] - M2), S2);
      float ln = (S2 > 0.f) ? (M2 + flog2(S2)) * LN2F : -INFINITY;

      // pad term with NEG_FILL bound (exact: true pad term underflows identically)
      int npad = counts[b * MAXC + c] - 1;
      float pt = (npad > 0) ? (logf((float)npad) + NEGFILL_T) : -INFINITY;
      float M = fmaxf(ps_, fmaxf(ln, pt));
      float lse = M + logf(expf(ps_ - M) + expf(ln - M) + expf(pt - M));
      out[b * NPATCH + outpos[n]] = lse - ps_;
    }
  }
}

extern "C" void kernel_launch(void* const* d_in, const int* in_sizes, int n_in,
                              void* d_out, int out_size, void* d_ws, size_t ws_size,
                              hipStream_t stream) {
  const float* src = (const float*)d_in[0];
  const float* tgt = (const float*)d_in[1];
  const int* cls   = (const int*)d_in[2];
  float* out = (float*)d_out;

  char* ws = (char*)d_ws;
  unsigned short* tgtb = (unsigned short*)(ws);            //  8,388,608 B (fragment layout)
  unsigned short* srcb = (unsigned short*)(ws + 8388608);  //  8,388,608 B (frag, pre-scaled)
  float* pos    = (float*)(ws + 16777216);                 //     65,536 B
  float* pm     = (float*)(ws + 16842752);                 //    524,288 B
  float* ps     = (float*)(ws + 17367040);                 //    524,288 B
  int*   outpos = (int*)  (ws + 17891328);                 //     65,536 B
  int*   counts = (int*)  (ws + 17956864);                 //        128 B
  unsigned int* cnt = (unsigned int*)(ws + 17956992);      //      1,024 B

  k_aux<<<512 + NBATCH + 1, 256, 0, stream>>>(src, tgt, cls, tgtb, srcb,
                                              pos, outpos, counts, cnt);
  k_main<<<NRBK * NSPLIT, 256, 0, stream>>>(srcb, tgtb, cls, pm, ps,
                                            pos, outpos, counts, cnt, out);
}

// Round 14
// 133.521 us; speedup vs baseline: 1.6333x; 1.6333x over previous
//
#include <hip/hip_runtime.h>
#include <cstdint>

#define NBATCH 4
#define NPATCH 4096
#define MAXC   5
#define BM 64
#define BN 64
#define NSPLIT 4
#define SPLITCOLS (NPATCH / NSPLIT)         /* 1024 cols per block */
#define NCIT (SPLITCOLS / BN)               /* 16 col-tiles per block */
#define SCALE  14.285714285714286f          /* 1/T, T=0.07 */
#define SCALE2 20.609929006188747f          /* (1/T) * log2(e) */
#define LN2F   0.6931471805599453f
#define NEGH  -1.0e38f
#define NEGFILL_T -142.85714285714286f      /* NEG_FILL / T */
#define NROWS (NBATCH * NPATCH)

typedef __attribute__((ext_vector_type(8))) short short8;   // 8 bf16 (4 VGPRs)
typedef __attribute__((ext_vector_type(4))) float f32x4;

__device__ __forceinline__ float fexp2(float x) { return __builtin_amdgcn_exp2f(x); }
__device__ __forceinline__ float flog2(float x) { return __builtin_amdgcn_logf(x); }  // v_log_f32 = log2

__device__ __forceinline__ unsigned short f2bf(float f) {
  uint32_t u = __builtin_bit_cast(uint32_t, f);
  u = (u + 0x7FFFu + ((u >> 16) & 1u)) >> 16;   // RNE
  return (unsigned short)u;
}

// Fragment layout (srcb and tgtb): tile = 16 rows x 256 k (8 KB).
// 16B chunk (8 bf16, one row's k-octet) at uint4 index  tile*512 + kc*16 + row16
// (kc = k/8, row16 = row%16).  A wave's fragment load (kc = ks*4+q, row = l4,
// lane = q*16+l4) is  base + ks*64 + lane : one fully-coalesced 1KB transaction.

// ---- k_aux: 2 roles ----
//  [0, 512):  single-pass: read src+tgt rows once -> srcb (pre-scaled bf16 frag),
//             tgtb (bf16 frag), AND exact-f32 pos via 8-lane shuffle reduce.
//  [512, 512+NBATCH): per-batch class scan (counts + stable ranks).
__global__ __launch_bounds__(256) void k_aux(const float* __restrict__ src,
                                             const float* __restrict__ tgt,
                                             const int* __restrict__ classes,
                                             unsigned short* __restrict__ tgtb,
                                             unsigned short* __restrict__ srcb,
                                             float* __restrict__ pos,
                                             int* __restrict__ outpos,
                                             int* __restrict__ counts) {
  int blk = blockIdx.x;
  if (blk < 512) {
    // block handles 2 tiles (32 rows); thread: one row's 32-k slab (8 threads/row)
    int t  = threadIdx.x;
    int tl = blk * 2 + (t >> 7);                 // tile index 0..1023
    int tt = t & 127;
    int row16 = tt >> 3;                         // 0..15
    int kg    = tt & 7;                          // 32 k each
    size_t rowbase = (size_t)(tl * 16 + row16) * 256 + kg * 32;
    const float4* rs = (const float4*)(src + rowbase);
    const float4* rt_ = (const float4*)(tgt + rowbase);
    uint4* wsrc = (uint4*)srcb + (size_t)tl * 512 + (size_t)(kg * 4) * 16 + row16;
    uint4* wtgt = (uint4*)tgtb + (size_t)tl * 512 + (size_t)(kg * 4) * 16 + row16;
    float d = 0.f;
#pragma unroll
    for (int j = 0; j < 4; ++j) {                // chunk kc = kg*4 + j
      float4 sa = rs[j * 2], sb = rs[j * 2 + 1];
      float4 ta = rt_[j * 2], tb = rt_[j * 2 + 1];
      d += sa.x * ta.x + sa.y * ta.y + sa.z * ta.z + sa.w * ta.w
         + sb.x * tb.x + sb.y * tb.y + sb.z * tb.z + sb.w * tb.w;
      union { ushort4 h[2]; uint4 u; } pk;
      pk.h[0].x = f2bf(sa.x * SCALE2); pk.h[0].y = f2bf(sa.y * SCALE2);
      pk.h[0].z = f2bf(sa.z * SCALE2); pk.h[0].w = f2bf(sa.w * SCALE2);
      pk.h[1].x = f2bf(sb.x * SCALE2); pk.h[1].y = f2bf(sb.y * SCALE2);
      pk.h[1].z = f2bf(sb.z * SCALE2); pk.h[1].w = f2bf(sb.w * SCALE2);
      wsrc[j * 16] = pk.u;
      pk.h[0].x = f2bf(ta.x); pk.h[0].y = f2bf(ta.y);
      pk.h[0].z = f2bf(ta.z); pk.h[0].w = f2bf(ta.w);
      pk.h[1].x = f2bf(tb.x); pk.h[1].y = f2bf(tb.y);
      pk.h[1].z = f2bf(tb.z); pk.h[1].w = f2bf(tb.w);
      wtgt[j * 16] = pk.u;
    }
    d += __shfl_xor(d, 1, 64);
    d += __shfl_xor(d, 2, 64);
    d += __shfl_xor(d, 4, 64);
    if (kg == 0) pos[tl * 16 + row16] = d * SCALE;
    return;
  }

  // ---- per-batch scan: counts + stable class-sorted output positions
  __shared__ int sa[MAXC * 256];
  __shared__ int sb2[MAXC * 256];
  int b = blk - 512, t = threadIdx.x;
  int base = b * NPATCH + t * 16;
  int cv[16];
#pragma unroll
  for (int e = 0; e < 16; ++e) cv[e] = classes[base + e];
  int cnt[MAXC];
#pragma unroll
  for (int c = 0; c < MAXC; ++c) {
    cnt[c] = 0;
#pragma unroll
    for (int e = 0; e < 16; ++e)
      if (cv[e] == c) cnt[c]++;
  }
#pragma unroll
  for (int c = 0; c < MAXC; ++c) sa[c * 256 + t] = cnt[c];
  __syncthreads();

  int* rp = sa; int* wp = sb2;
  for (int d = 1; d < 256; d <<= 1) {            // Hillis-Steele inclusive scan
#pragma unroll
    for (int c = 0; c < MAXC; ++c) {
      int v = rp[c * 256 + t];
      if (t >= d) v += rp[c * 256 + t - d];
      wp[c * 256 + t] = v;
    }
    __syncthreads();
    int* tmp = rp; rp = wp; wp = tmp;
  }

  int tot[MAXC], excl[MAXC], off[MAXC + 1];
  off[0] = 0;
#pragma unroll
  for (int c = 0; c < MAXC; ++c) {
    tot[c]  = rp[c * 256 + 255];
    excl[c] = rp[c * 256 + t] - cnt[c];
    off[c + 1] = off[c] + tot[c];
  }
#pragma unroll
  for (int c = 0; c < MAXC; ++c) {
    int r = off[c] + excl[c];
#pragma unroll
    for (int e = 0; e < 16; ++e)
      if (cv[e] == c) { outpos[base + e] = r; r++; }
  }
  if (t < MAXC) counts[b * MAXC + t] = tot[t];
}

// ---------------- main fused GEMM + online lse stats (barrier-free K-loop) -------------
// R11 structure exactly (free-running waves, register ping-pong prefetch, stats on
// prev tile between prefetches), NSPLIT=4: grid 1024 = 4 blocks/CU exactly matches
// the VGPR-limited residency; A-fragment L2 traffic halves vs NSPLIT=8.
__global__ __launch_bounds__(256) void k_main(const unsigned short* __restrict__ srcb,
                                              const unsigned short* __restrict__ tgtb,
                                              const int* __restrict__ classes,
                                              float* __restrict__ pm,
                                              float* __restrict__ ps) {
  __shared__ float redm[2][BM], reds[2][BM];

  const int blk   = blockIdx.x;
  const int split = blk & (NSPLIT - 1);
  const int rbk   = blk >> 2;
  const int b     = rbk >> 6;
  const int rb    = rbk & 63;
  const int rowstart = b * NPATCH + rb * BM;
  const int tid = threadIdx.x;
  const int w = tid >> 6, lane = tid & 63, q = lane >> 4, l4 = lane & 15;
  const int rh = w >> 1, ch = w & 1;
  const int colbase = b * NPATCH + split * SPLITCOLS;

  // ---- A fragments: 16 coalesced uint4 loads (pre-scaled bf16, fragment layout)
  const uint4* ap = (const uint4*)srcb + (size_t)(b * 256 + rb * 4 + rh * 2) * 512 + lane;
  uint4 afr[2][8];
#pragma unroll
  for (int rt = 0; rt < 2; ++rt)
#pragma unroll
    for (int ks = 0; ks < 8; ++ks)
      afr[rt][ks] = ap[rt * 512 + ks * 64];

  int rcls[2][4];
#pragma unroll
  for (int rt = 0; rt < 2; ++rt)
#pragma unroll
    for (int r = 0; r < 4; ++r)
      rcls[rt][r] = classes[rowstart + rh * 32 + rt * 16 + q * 4 + r];

  float m_[2][4], s_[2][4];
#pragma unroll
  for (int rt = 0; rt < 2; ++rt)
#pragma unroll
    for (int r = 0; r < 4; ++r) { m_[rt][r] = -INFINITY; s_[rt][r] = 0.f; }

  // ---- B-fragment pointer: wave's ch half starts at tile (b*256 + split*64 + ch*2)
  const uint4* bp = (const uint4*)tgtb
                  + (size_t)(b * 256 + split * 64 + ch * 2) * 512 + lane;
  const int* clp = classes + colbase + ch * 32 + l4;

  uint4 ea0[4], ea1[4], eb0[4], eb1[4];
#define LOADH(d0, d1, uoff)                                                         \
  {                                                                                 \
    _Pragma("unroll")                                                               \
    for (int i = 0; i < 4; ++i) {                                                   \
      d0[i] = bp[(uoff) + i * 64];                                                  \
      d1[i] = bp[(uoff) + i * 64 + 512];                                            \
    }                                                                               \
  }

#define STATS(ac, cc0, cc1)                                                         \
  {                                                                                 \
    _Pragma("unroll")                                                               \
    for (int rt = 0; rt < 2; ++rt) {                                                \
      _Pragma("unroll")                                                             \
      for (int r = 0; r < 4; ++r) {                                                 \
        int rc = rcls[rt][r];                                                       \
        float y0 = ((cc0) == rc) ? NEGH : (ac)[rt][0][r];                           \
        float y1 = ((cc1) == rc) ? NEGH : (ac)[rt][1][r];                           \
        float nm = fmaxf(m_[rt][r], fmaxf(y0, y1));                                 \
        float e01 = fexp2(y0 - nm) + fexp2(y1 - nm);                                \
        s_[rt][r] = fmaf(s_[rt][r], fexp2(m_[rt][r] - nm), e01);                    \
        m_[rt][r] = nm;                                                             \
      }                                                                             \
    }                                                                               \
  }

  LOADH(ea0, ea1, 0);                            // prologue: (cit0, kh0)

  const f32x4 zc = {0.f, 0.f, 0.f, 0.f};         // zero C operand (first MFMA of tile)
  f32x4 pacc[2][2];
  int pc0 = 0, pc1 = 0;

  for (int cit = 0; cit < NCIT; ++cit) {
    f32x4 acc[2][2];

    LOADH(eb0, eb1, cit * 2048 + 256);           // prefetch kh=1 of this tile
    int c0 = clp[cit * 64];
    int c1 = clp[cit * 64 + 16];

    // compute kh=0 from ea (eb loads in flight); first ksl uses zero-C
#pragma unroll
    for (int ksl = 0; ksl < 4; ++ksl) {
      short8 b0 = __builtin_bit_cast(short8, ea0[ksl]);
      short8 b1 = __builtin_bit_cast(short8, ea1[ksl]);
#pragma unroll
      for (int rt = 0; rt < 2; ++rt) {
        short8 a = __builtin_bit_cast(short8, afr[rt][ksl]);
        acc[rt][0] = __builtin_amdgcn_mfma_f32_16x16x32_bf16(
            a, b0, (ksl == 0) ? zc : acc[rt][0], 0, 0, 0);
        acc[rt][1] = __builtin_amdgcn_mfma_f32_16x16x32_bf16(
            a, b1, (ksl == 0) ? zc : acc[rt][1], 0, 0, 0);
      }
    }

    if (cit + 1 < NCIT) LOADH(ea0, ea1, (cit + 1) * 2048);   // prefetch next tile kh=0

    // stats on PREVIOUS tile's acc — covers both in-flight prefetches with VALU
    if (cit > 0) STATS(pacc, pc0, pc1);

    // compute kh=1 from eb
#pragma unroll
    for (int ksl = 0; ksl < 4; ++ksl) {
      short8 b0 = __builtin_bit_cast(short8, eb0[ksl]);
      short8 b1 = __builtin_bit_cast(short8, eb1[ksl]);
#pragma unroll
      for (int rt = 0; rt < 2; ++rt) {
        short8 a = __builtin_bit_cast(short8, afr[rt][4 + ksl]);
        acc[rt][0] = __builtin_amdgcn_mfma_f32_16x16x32_bf16(a, b0, acc[rt][0], 0, 0, 0);
        acc[rt][1] = __builtin_amdgcn_mfma_f32_16x16x32_bf16(a, b1, acc[rt][1], 0, 0, 0);
      }
    }

#pragma unroll
    for (int rt = 0; rt < 2; ++rt)
#pragma unroll
      for (int ct = 0; ct < 2; ++ct) pacc[rt][ct] = acc[rt][ct];
    pc0 = c0; pc1 = c1;
  }
  STATS(pacc, pc0, pc1);                         // epilogue: last tile's stats
#undef LOADH
#undef STATS

  // butterfly merge across the 16 col-lanes of each quad
#pragma unroll
  for (int off = 1; off < 16; off <<= 1) {
#pragma unroll
    for (int rt = 0; rt < 2; ++rt)
#pragma unroll
      for (int r = 0; r < 4; ++r) {
        float om = __shfl_xor(m_[rt][r], off, 64);
        float os = __shfl_xor(s_[rt][r], off, 64);
        float nm = fmaxf(m_[rt][r], om);
        s_[rt][r] = s_[rt][r] * fexp2(m_[rt][r] - nm) + os * fexp2(om - nm);
        m_[rt][r] = nm;
      }
  }

  if (l4 == 0) {
#pragma unroll
    for (int rt = 0; rt < 2; ++rt)
#pragma unroll
      for (int r = 0; r < 4; ++r) {
        int li = rh * 32 + rt * 16 + q * 4 + r;
        redm[ch][li] = m_[rt][r];
        reds[ch][li] = s_[rt][r];
      }
  }
  __syncthreads();
  if (tid < BM) {
    float m0 = redm[0][tid], m1 = redm[1][tid];
    float nm = fmaxf(m0, m1);
    float s  = reds[0][tid] * fexp2(m0 - nm) + reds[1][tid] * fexp2(m1 - nm);
    size_t o = (size_t)split * NROWS + rowstart + tid;
    pm[o] = nm;                                   // log2 domain
    ps[o] = s;
  }
}

// ---------------- final: merge split partials + pad term + scatter (grid 64) ----------
__global__ __launch_bounds__(256) void k_fin(const int* __restrict__ classes,
                                             const float* __restrict__ pos,
                                             const float* __restrict__ pm,
                                             const float* __restrict__ ps,
                                             const int* __restrict__ outpos,
                                             const int* __restrict__ counts,
                                             float* __restrict__ out) {
  int n = blockIdx.x * 256 + threadIdx.x;
  int b = n >> 12;
  int c = classes[n];
  float ps_ = pos[n];

  float M2 = -INFINITY;
  float mm[NSPLIT], ss[NSPLIT];
#pragma unroll
  for (int s = 0; s < NSPLIT; ++s) {
    mm[s] = pm[(size_t)s * NROWS + n];
    ss[s] = ps[(size_t)s * NROWS + n];
    M2 = fmaxf(M2, mm[s]);
  }
  float S2 = 0.f;
#pragma unroll
  for (int s = 0; s < NSPLIT; ++s) S2 = fmaf(ss[s], fexp2(mm[s] - M2), S2);
  float ln = (S2 > 0.f) ? (M2 + flog2(S2)) * LN2F : -INFINITY;

  // pad term with NEG_FILL bound (exact: true pad term underflows identically in fp32)
  int npad = counts[b * MAXC + c] - 1;
  float pt = (npad > 0) ? (logf((float)npad) + NEGFILL_T) : -INFINITY;
  float M = fmaxf(ps_, fmaxf(ln, pt));
  float lse = M + logf(expf(ps_ - M) + expf(ln - M) + expf(pt - M));
  out[b * NPATCH + outpos[n]] = lse - ps_;
}

extern "C" void kernel_launch(void* const* d_in, const int* in_sizes, int n_in,
                              void* d_out, int out_size, void* d_ws, size_t ws_size,
                              hipStream_t stream) {
  const float* src = (const float*)d_in[0];
  const float* tgt = (const float*)d_in[1];
  const int* cls   = (const int*)d_in[2];
  float* out = (float*)d_out;

  char* ws = (char*)d_ws;
  unsigned short* tgtb = (unsigned short*)(ws);            //  8,388,608 B (fragment layout)
  unsigned short* srcb = (unsigned short*)(ws + 8388608);  //  8,388,608 B (frag, pre-scaled)
  float* pos    = (float*)(ws + 16777216);                 //     65,536 B
  float* pm     = (float*)(ws + 16842752);                 //    262,144 B
  float* ps     = (float*)(ws + 17104896);                 //    262,144 B
  int*   outpos = (int*)  (ws + 17367040);                 //     65,536 B
  int*   counts = (int*)  (ws + 17432576);                 //         80 B

  k_aux<<<512 + NBATCH, 256, 0, stream>>>(src, tgt, cls, tgtb, srcb, pos, outpos, counts);
  k_main<<<NBATCH * (NPATCH / BM) * NSPLIT, 256, 0, stream>>>(srcb, tgtb, cls, pm, ps);
  k_fin<<<NROWS / 256, 256, 0, stream>>>(cls, pos, pm, ps, outpos, counts, out);
}